// Round 3
// baseline (325.237 us; speedup 1.0000x reference)
//
#include <hip/hip_runtime.h>
#include <hip/hip_bf16.h>
#include <stdint.h>

#define N_NODES 100000
#define DEG 16
#define D_IN 128
#define D_OUT 256
#define K_TOP 32
#define K_CAT 256   // concatenated K = D_IN(self) + D_IN(neigh)

typedef __attribute__((ext_vector_type(8))) short short8;
typedef __attribute__((ext_vector_type(4))) float floatx4;

__device__ __forceinline__ unsigned pack_bf16_rne(float f) {
    union { float f; unsigned u; } c; c.f = f;
    unsigned u = c.u;
    return (u + 0x7fffu + ((u >> 16) & 1u)) >> 16;   // round-to-nearest-even
}
__device__ __forceinline__ float bf16lo_to_f(unsigned lo16) {
    union { unsigned u; float f; } c; c.u = lo16 << 16; return c.f;
}

// ---------------- kernel 1: pack [w_self | w_neigh] -> bf16 B[256][256] ----------------
__global__ __launch_bounds__(256) void k_packw(const float* __restrict__ w_self,
                                               const float* __restrict__ w_neigh,
                                               unsigned short* __restrict__ bmat) {
    int o = blockIdx.x;      // 0..255 output channel
    int k = threadIdx.x;     // 0..255 concat-K
    float v = (k < D_IN) ? w_self[o * D_IN + k] : w_neigh[o * D_IN + (k - D_IN)];
    bmat[o * K_CAT + k] = (unsigned short)pack_bf16_rne(v);
}

// ---------------- kernel 2: densify (wave-per-row, register-only) + feat->bf16 ---------
// Lane l owns cols {2l, 2l+1}. 32 (idx,val) pairs broadcast by shuffle; fp32 compare-add
// handles duplicate indices. Also converts this row's feat into A's left half.
__global__ __launch_bounds__(256) void k_densify(const float* __restrict__ topk_v,
                                                 const int* __restrict__ topk_i,
                                                 const float* __restrict__ feat,
                                                 unsigned short* __restrict__ xbf,
                                                 unsigned short* __restrict__ abf) {
    int wave = threadIdx.x >> 6;
    int lane = threadIdx.x & 63;
    int row  = blockIdx.x * 4 + wave;
    if (row >= N_NODES) return;

    int   ix = 0; float v = 0.f;
    if (lane < K_TOP) {
        ix = topk_i[row * K_TOP + lane];
        v  = topk_v[row * K_TOP + lane];
    }
    const int c0 = 2 * lane, c1 = 2 * lane + 1;
    float a0 = 0.f, a1 = 0.f;
    #pragma unroll
    for (int j = 0; j < K_TOP; ++j) {
        int   idx = __shfl(ix, j);
        float val = __shfl(v, j);
        a0 += (idx == c0) ? val : 0.f;
        a1 += (idx == c1) ? val : 0.f;
    }
    unsigned xp = pack_bf16_rne(a0) | (pack_bf16_rne(a1) << 16);
    ((unsigned*)(xbf + (size_t)row * D_IN))[lane] = xp;

    // feat -> bf16 into A's left half (cols 0..127 of K_CAT)
    const float2 f2 = *(const float2*)(feat + (size_t)row * D_IN + c0);
    unsigned fp = pack_bf16_rne(f2.x) | (pack_bf16_rne(f2.y) << 16);
    ((unsigned*)(abf + (size_t)row * K_CAT))[lane] = fp;
}

// ---------------- kernel 3: SpMM (wave-per-row), 16 outstanding gathers ----------------
__global__ __launch_bounds__(256) void k_spmm(const float* __restrict__ csr_w,
                                              const int* __restrict__ col_idx,
                                              const unsigned short* __restrict__ xbf,
                                              unsigned short* __restrict__ abf) {
    int wave = threadIdx.x >> 6;
    int lane = threadIdx.x & 63;
    int row  = blockIdx.x * 4 + wave;
    if (row >= N_NODES) return;

    int c = 0; float w = 0.f;
    if (lane < DEG) {
        c = col_idx[row * DEG + lane];
        w = csr_w[row * DEG + lane];
    }
    // issue all 16 gathers first (independent, 16 outstanding vmem loads)
    unsigned vv[DEG];
    #pragma unroll
    for (int e = 0; e < DEG; ++e) {
        int col = __shfl(c, e);
        vv[e] = ((const unsigned*)(xbf + (size_t)col * D_IN))[lane]; // 2 bf16
    }
    float a0 = 0.f, a1 = 0.f;
    #pragma unroll
    for (int e = 0; e < DEG; ++e) {
        float we = __shfl(w, e);
        a0 += we * bf16lo_to_f(vv[e] & 0xffffu);
        a1 += we * bf16lo_to_f(vv[e] >> 16);
    }
    unsigned ap = pack_bf16_rne(a0) | (pack_bf16_rne(a1) << 16);
    ((unsigned*)(abf + (size_t)row * K_CAT + D_IN))[lane] = ap;
}

// ------------- kernel 4: GEMM  out[N][256] = A[N][256] @ B[256][256]^T + bias ----------
// BM=128 rows, BN=256 (= full D_OUT, so A is read exactly once), BK=32.
// 2x2 waves; each wave 64 rows x 128 cols = 4x8 mfma_f32_16x16x32_bf16 frags.
#define BM 128
#define BN 256
#define BK 32
#define LDP 40   // padded LDS row stride in shorts (80 B -> 2-way bank alias, free)

__global__ __launch_bounds__(256, 2) void k_gemm(const unsigned short* __restrict__ abf,
                                                 const unsigned short* __restrict__ bmat,
                                                 const float* __restrict__ bias,
                                                 float* __restrict__ out) {
    __shared__ unsigned short As[BM * LDP];   // 10 KiB
    __shared__ unsigned short Bs[BN * LDP];   // 20 KiB
    int t = threadIdx.x;
    int lane = t & 63, wave = t >> 6;
    int wr = wave >> 1, wc = wave & 1;        // 2x2 wave grid; wave = 64 rows x 128 cols
    int row0 = blockIdx.x * BM;

    floatx4 acc[4][8];
    #pragma unroll
    for (int i = 0; i < 4; ++i)
        #pragma unroll
        for (int j = 0; j < 8; ++j)
            acc[i][j] = (floatx4){0.f, 0.f, 0.f, 0.f};

    int quad = lane >> 4;
    int l16  = lane & 15;

    for (int kt = 0; kt < K_CAT; kt += BK) {
        __syncthreads();
        // A tile: 128 rows x 32 shorts (64 B/row) = 512 x 16B chunks -> 2/thread
        #pragma unroll
        for (int p = 0; p < 2; ++p) {
            int chunk = t + p * 256;
            int r  = chunk >> 2;               // 0..127
            int ko = (chunk & 3) * 8;          // 0,8,16,24
            uint4 av = make_uint4(0u, 0u, 0u, 0u);
            int gr = row0 + r;
            if (gr < N_NODES)
                av = *(const uint4*)(abf + (size_t)gr * K_CAT + kt + ko);
            *(uint4*)&As[r * LDP + ko] = av;
        }
        // B tile: 256 rows x 32 shorts = 1024 x 16B chunks -> 4/thread
        #pragma unroll
        for (int p = 0; p < 4; ++p) {
            int chunk = t + p * 256;
            int r  = chunk >> 2;               // 0..255
            int ko = (chunk & 3) * 8;
            uint4 bv = *(const uint4*)(bmat + (size_t)r * K_CAT + kt + ko);
            *(uint4*)&Bs[r * LDP + ko] = bv;
        }
        __syncthreads();

        short8 afr[4], bfr[8];
        #pragma unroll
        for (int i = 0; i < 4; ++i) {
            int m = wr * 64 + i * 16 + l16;    // A frag: m=lane&15, k=quad*8+j
            afr[i] = *(const short8*)&As[m * LDP + quad * 8];
        }
        #pragma unroll
        for (int j = 0; j < 8; ++j) {
            int n = wc * 128 + j * 16 + l16;   // B frag: n=lane&15, k=quad*8+j
            bfr[j] = *(const short8*)&Bs[n * LDP + quad * 8];
        }
        #pragma unroll
        for (int i = 0; i < 4; ++i)
            #pragma unroll
            for (int j = 0; j < 8; ++j)
                acc[i][j] = __builtin_amdgcn_mfma_f32_16x16x32_bf16(afr[i], bfr[j], acc[i][j], 0, 0, 0);
    }

    // epilogue: D frag mapping col=lane&15, row=quad*4+reg
    #pragma unroll
    for (int j = 0; j < 8; ++j) {
        int cg = wc * 128 + j * 16 + l16;
        float bv = bias[cg];
        #pragma unroll
        for (int i = 0; i < 4; ++i) {
            int mbase = row0 + wr * 64 + i * 16 + quad * 4;
            #pragma unroll
            for (int r = 0; r < 4; ++r) {
                int gr = mbase + r;
                if (gr < N_NODES) out[(size_t)gr * D_OUT + cg] = acc[i][j][r] + bv;
            }
        }
    }
}

extern "C" void kernel_launch(void* const* d_in, const int* in_sizes, int n_in,
                              void* d_out, int out_size, void* d_ws, size_t ws_size,
                              hipStream_t stream) {
    const float* feat    = (const float*)d_in[0];
    const float* topk_v  = (const float*)d_in[1];
    const float* csr_w   = (const float*)d_in[2];
    const float* w_neigh = (const float*)d_in[3];
    const float* w_self  = (const float*)d_in[4];
    const float* b_self  = (const float*)d_in[5];
    const int*   topk_i  = (const int*)d_in[6];
    // d_in[7] = indptr (fixed degree 16, unused), d_in[8] = indices
    const int*   indices = (const int*)d_in[8];
    float* out = (float*)d_out;

    // workspace layout (bf16): x[N*128] | A[N*256] | B[256*256]  (~77 MB)
    unsigned short* xbf  = (unsigned short*)d_ws;
    unsigned short* abf  = xbf + (size_t)N_NODES * D_IN;
    unsigned short* bmat = abf + (size_t)N_NODES * K_CAT;

    k_packw<<<dim3(256), dim3(256), 0, stream>>>(w_self, w_neigh, bmat);
    k_densify<<<dim3(N_NODES / 4), dim3(256), 0, stream>>>(topk_v, topk_i, feat, xbf, abf);
    k_spmm<<<dim3(N_NODES / 4), dim3(256), 0, stream>>>(csr_w, indices, xbf, abf);
    k_gemm<<<dim3((N_NODES + BM - 1) / BM), dim3(256), 0, stream>>>(abf, bmat, b_self, out);
}

// Round 4
// 308.212 us; speedup vs baseline: 1.0552x; 1.0552x over previous
//
#include <hip/hip_runtime.h>
#include <hip/hip_bf16.h>
#include <stdint.h>

#define N_NODES 100000
#define DEG 16
#define D_IN 128
#define D_OUT 256
#define K_TOP 32
#define K_CAT 256   // concatenated K = D_IN(self) + D_IN(neigh)

typedef __attribute__((ext_vector_type(8))) short short8;
typedef __attribute__((ext_vector_type(4))) float floatx4;

__device__ __forceinline__ unsigned pack_bf16_rne(float f) {
    union { float f; unsigned u; } c; c.f = f;
    unsigned u = c.u;
    return (u + 0x7fffu + ((u >> 16) & 1u)) >> 16;   // round-to-nearest-even
}
__device__ __forceinline__ float bf16lo_to_f(unsigned lo16) {
    union { unsigned u; float f; } c; c.u = lo16 << 16; return c.f;
}

// ---------------- kernel 1: pack [w_self | w_neigh] -> bf16 B[256][256] ----------------
__global__ __launch_bounds__(256) void k_packw(const float* __restrict__ w_self,
                                               const float* __restrict__ w_neigh,
                                               unsigned short* __restrict__ bmat) {
    int o = blockIdx.x;      // 0..255 output channel
    int k = threadIdx.x;     // 0..255 concat-K
    float v = (k < D_IN) ? w_self[o * D_IN + k] : w_neigh[o * D_IN + (k - D_IN)];
    bmat[o * K_CAT + k] = (unsigned short)pack_bf16_rne(v);
}

// ------------- kernel 2: densify via LDS ds_add_f32 scatter + feat->bf16 ---------------
// 64 rows/block. Coalesced topk reads, one LDS float atomic per (row,j) pair (duplicate
// indices handled by HW add), then coalesced bf16 pack of x and feat (A left half).
#define DROWS 64
__global__ __launch_bounds__(256) void k_densify(const float* __restrict__ topk_v,
                                                 const int* __restrict__ topk_i,
                                                 const float* __restrict__ feat,
                                                 unsigned short* __restrict__ xbf,
                                                 unsigned short* __restrict__ abf) {
    __shared__ float sx[DROWS * D_IN];   // 32 KiB
    const int t = threadIdx.x;
    const int row0 = blockIdx.x * DROWS;

    // zero LDS: 8192 floats / 256 thr = 8 float4 per thread
    #pragma unroll
    for (int p = 0; p < 8; ++p)
        *(floatx4*)&sx[(t + p * 256) * 4] = (floatx4){0.f, 0.f, 0.f, 0.f};
    __syncthreads();

    // scatter: 64 rows x 32 pairs = 2048 pairs, 8 per thread, coalesced reads
    const size_t tbase = (size_t)row0 * K_TOP;
    #pragma unroll
    for (int p = 0; p < 8; ++p) {
        int q = t + p * 256;             // 0..2047
        int r = q >> 5;                  // 0..63
        if (row0 + r < N_NODES) {
            int   ci = topk_i[tbase + q];
            float cv = topk_v[tbase + q];
            atomicAdd(&sx[r * D_IN + ci], cv);   // ds_add_f32, no return
        }
    }
    __syncthreads();

    // pack x -> bf16, coalesced: 4096 dwords, 16 per thread
    #pragma unroll
    for (int p = 0; p < 16; ++p) {
        int d = t + p * 256;             // dword index 0..4095
        int r = d >> 6;                  // 0..63
        int c2 = (d & 63) * 2;
        if (row0 + r < N_NODES) {
            float2 v = *(const float2*)&sx[r * D_IN + c2];
            ((unsigned*)(xbf + (size_t)(row0 + r) * D_IN))[d & 63] =
                pack_bf16_rne(v.x) | (pack_bf16_rne(v.y) << 16);
        }
    }

    // feat -> bf16 into A left half: 2048 float4, 8 per thread
    #pragma unroll
    for (int p = 0; p < 8; ++p) {
        int q = t + p * 256;             // 0..2047
        int r = q >> 5;                  // 0..63
        int c4 = (q & 31) * 4;
        if (row0 + r < N_NODES) {
            float4 f = *(const float4*)(feat + (size_t)(row0 + r) * D_IN + c4);
            uint2 pk;
            pk.x = pack_bf16_rne(f.x) | (pack_bf16_rne(f.y) << 16);
            pk.y = pack_bf16_rne(f.z) | (pack_bf16_rne(f.w) << 16);
            ((uint2*)(abf + (size_t)(row0 + r) * K_CAT))[q & 31] = pk;
        }
    }
}

// --------- kernel 3: SpMM — 2 rows per wave (half-wave per row), dwordx2 gathers -------
__global__ __launch_bounds__(256) void k_spmm(const float* __restrict__ csr_w,
                                              const int* __restrict__ col_idx,
                                              const unsigned short* __restrict__ xbf,
                                              unsigned short* __restrict__ abf) {
    const int wave = threadIdx.x >> 6;
    const int lane = threadIdx.x & 63;
    const int pair = blockIdx.x * 4 + wave;
    const int row  = 2 * pair + (lane >> 5);    // half-wave per row
    const int hl   = lane & 31;
    if (row >= N_NODES) return;

    int c = 0; float w = 0.f;
    if (hl < DEG) {
        c = col_idx[row * DEG + hl];
        w = csr_w[row * DEG + hl];
    }
    const int bsel = lane & 32;
    // issue all 16 gathers (8 B/lane, 32 lanes/row => 256 B per row per instr)
    uint2 vv[DEG];
    #pragma unroll
    for (int e = 0; e < DEG; ++e) {
        int col = __shfl(c, bsel | e);
        vv[e] = *(const uint2*)(xbf + (size_t)col * D_IN + hl * 4);
    }
    float a0 = 0.f, a1 = 0.f, a2 = 0.f, a3 = 0.f;
    #pragma unroll
    for (int e = 0; e < DEG; ++e) {
        float we = __shfl(w, bsel | e);
        a0 += we * bf16lo_to_f(vv[e].x & 0xffffu);
        a1 += we * bf16lo_to_f(vv[e].x >> 16);
        a2 += we * bf16lo_to_f(vv[e].y & 0xffffu);
        a3 += we * bf16lo_to_f(vv[e].y >> 16);
    }
    uint2 pk;
    pk.x = pack_bf16_rne(a0) | (pack_bf16_rne(a1) << 16);
    pk.y = pack_bf16_rne(a2) | (pack_bf16_rne(a3) << 16);
    ((uint2*)(abf + (size_t)row * K_CAT + D_IN))[hl] = pk;
}

// ------------- kernel 4: GEMM  out[N][256] = A[N][256] @ B[256][256]^T + bias ----------
// BM=128 rows, BN=256 (= full D_OUT, so A is read exactly once), BK=32.
// 2x2 waves; each wave 64 rows x 128 cols = 4x8 mfma_f32_16x16x32_bf16 frags.
#define BM 128
#define BN 256
#define BK 32
#define LDP 40   // padded LDS row stride in shorts (80 B -> 2-way bank alias, free)

__global__ __launch_bounds__(256, 2) void k_gemm(const unsigned short* __restrict__ abf,
                                                 const unsigned short* __restrict__ bmat,
                                                 const float* __restrict__ bias,
                                                 float* __restrict__ out) {
    __shared__ unsigned short As[BM * LDP];   // 10 KiB
    __shared__ unsigned short Bs[BN * LDP];   // 20 KiB
    int t = threadIdx.x;
    int lane = t & 63, wave = t >> 6;
    int wr = wave >> 1, wc = wave & 1;        // 2x2 wave grid; wave = 64 rows x 128 cols
    int row0 = blockIdx.x * BM;

    floatx4 acc[4][8];
    #pragma unroll
    for (int i = 0; i < 4; ++i)
        #pragma unroll
        for (int j = 0; j < 8; ++j)
            acc[i][j] = (floatx4){0.f, 0.f, 0.f, 0.f};

    int quad = lane >> 4;
    int l16  = lane & 15;

    for (int kt = 0; kt < K_CAT; kt += BK) {
        __syncthreads();
        // A tile: 128 rows x 32 shorts (64 B/row) = 512 x 16B chunks -> 2/thread
        #pragma unroll
        for (int p = 0; p < 2; ++p) {
            int chunk = t + p * 256;
            int r  = chunk >> 2;               // 0..127
            int ko = (chunk & 3) * 8;          // 0,8,16,24
            uint4 av = make_uint4(0u, 0u, 0u, 0u);
            int gr = row0 + r;
            if (gr < N_NODES)
                av = *(const uint4*)(abf + (size_t)gr * K_CAT + kt + ko);
            *(uint4*)&As[r * LDP + ko] = av;
        }
        // B tile: 256 rows x 32 shorts = 1024 x 16B chunks -> 4/thread
        #pragma unroll
        for (int p = 0; p < 4; ++p) {
            int chunk = t + p * 256;
            int r  = chunk >> 2;               // 0..255
            int ko = (chunk & 3) * 8;
            uint4 bv = *(const uint4*)(bmat + (size_t)r * K_CAT + kt + ko);
            *(uint4*)&Bs[r * LDP + ko] = bv;
        }
        __syncthreads();

        short8 afr[4], bfr[8];
        #pragma unroll
        for (int i = 0; i < 4; ++i) {
            int m = wr * 64 + i * 16 + l16;    // A frag: m=lane&15, k=quad*8+j
            afr[i] = *(const short8*)&As[m * LDP + quad * 8];
        }
        #pragma unroll
        for (int j = 0; j < 8; ++j) {
            int n = wc * 128 + j * 16 + l16;   // B frag: n=lane&15, k=quad*8+j
            bfr[j] = *(const short8*)&Bs[n * LDP + quad * 8];
        }
        #pragma unroll
        for (int i = 0; i < 4; ++i)
            #pragma unroll
            for (int j = 0; j < 8; ++j)
                acc[i][j] = __builtin_amdgcn_mfma_f32_16x16x32_bf16(afr[i], bfr[j], acc[i][j], 0, 0, 0);
    }

    // epilogue: D frag mapping col=lane&15, row=quad*4+reg
    #pragma unroll
    for (int j = 0; j < 8; ++j) {
        int cg = wc * 128 + j * 16 + l16;
        float bv = bias[cg];
        #pragma unroll
        for (int i = 0; i < 4; ++i) {
            int mbase = row0 + wr * 64 + i * 16 + quad * 4;
            #pragma unroll
            for (int r = 0; r < 4; ++r) {
                int gr = mbase + r;
                if (gr < N_NODES) out[(size_t)gr * D_OUT + cg] = acc[i][j][r] + bv;
            }
        }
    }
}

extern "C" void kernel_launch(void* const* d_in, const int* in_sizes, int n_in,
                              void* d_out, int out_size, void* d_ws, size_t ws_size,
                              hipStream_t stream) {
    const float* feat    = (const float*)d_in[0];
    const float* topk_v  = (const float*)d_in[1];
    const float* csr_w   = (const float*)d_in[2];
    const float* w_neigh = (const float*)d_in[3];
    const float* w_self  = (const float*)d_in[4];
    const float* b_self  = (const float*)d_in[5];
    const int*   topk_i  = (const int*)d_in[6];
    // d_in[7] = indptr (fixed degree 16, unused), d_in[8] = indices
    const int*   indices = (const int*)d_in[8];
    float* out = (float*)d_out;

    // workspace layout (bf16): x[N*128] | A[N*256] | B[256*256]  (~77 MB)
    unsigned short* xbf  = (unsigned short*)d_ws;
    unsigned short* abf  = xbf + (size_t)N_NODES * D_IN;
    unsigned short* bmat = abf + (size_t)N_NODES * K_CAT;

    k_packw<<<dim3(256), dim3(256), 0, stream>>>(w_self, w_neigh, bmat);
    k_densify<<<dim3((N_NODES + DROWS - 1) / DROWS), dim3(256), 0, stream>>>(topk_v, topk_i, feat, xbf, abf);
    k_spmm<<<dim3((N_NODES + 7) / 8), dim3(256), 0, stream>>>(csr_w, indices, xbf, abf);
    k_gemm<<<dim3((N_NODES + BM - 1) / BM), dim3(256), 0, stream>>>(abf, bmat, b_self, out);
}